// Round 16
// baseline (147.515 us; speedup 1.0000x reference)
//
#include <hip/hip_runtime.h>

#define HH 256
#define WW 256
#define NB 4
#define NC 4
#define NPIX (HH*WW)            // 65536
#define NIMG (NB*NC)            // 16
#define TOTAL (NB*NC*HH*WW)     // 1048576
#define INF_G (1<<30)
#define PAD 257

__device__ __forceinline__ float wave_reduce(float v) {
    #pragma unroll
    for (int off = 32; off > 0; off >>= 1) v += __shfl_down(v, off);
    return v;
}

// distance from x to nearest set bit in a 256-bit mask (4 u64 words); INT_MAX if none
__device__ __forceinline__ int nearest_dist(const unsigned long long* m, int x) {
    int best = 0x7fffffff;
    #pragma unroll
    for (int w = 0; w < 4; ++w) {
        unsigned long long mm = m[w];
        if (!mm) continue;
        int rel = x - (w << 6);
        unsigned long long lmask = (rel >= 63) ? ~0ull
                                 : ((rel < 0) ? 0ull : ((2ull << (rel & 63)) - 1ull));
        unsigned long long lm = mm & lmask;
        if (lm) best = min(best, rel - (63 - __clzll(lm)));
        unsigned long long rmask = (rel <= 0) ? ~0ull
                                 : ((rel > 63) ? 0ull : (~0ull << (rel & 63)));
        unsigned long long rm = mm & rmask;
        if (rm) best = min(best, (__ffsll((long long)rm) - 1) - rel);
    }
    return best;
}

// ONE kernel, 512 blocks x 512 threads (4096 waves = 50% capacity -> all co-resident).
// Producer (blocks 0..255): row ballot masks for 4 rows of batch b (r13's k1 logic),
//   then release-fence + atomicAdd(ready[b]).
// Consumer (all 512 blocks): (img, 8-col strip); t0 spins until ready[b]==64 (acquire),
//   then r12's verified phases A/B; per-block atomic into ws_out; the 512th block
//   copies the total into out[0] (no pre-zero of out needed).
// ctrl (ready[4], done, ws_out) is memset to 0 each call by a tiny SDMA node.
__global__ __launch_bounds__(512) void fused_all(
        const float* __restrict__ pred, const int* __restrict__ target,
        unsigned long long* __restrict__ masks,
        int* __restrict__ ready, int* __restrict__ done, float* __restrict__ ws_out,
        float* __restrict__ out) {
    int bid = blockIdx.x;
    int t = threadIdx.x;
    int lane = t & 63, wv = t >> 6;

    // ---------------- producer ----------------
    if (bid < 256) {
        int b = bid >> 6, rg = bid & 63;
        int x = t & 255;
        int w = x >> 6;                 // word index within the row (uniform per wave)
        #pragma unroll
        for (int j = 0; j < 2; ++j) {
            int y = (rg << 2) + (t >> 8) + 2 * j;   // rows rg*4 + {0,1,2,3}

            const float* base = pred + (((size_t)b * NC) * HH + y) * WW + x;
            float v0 = base[0 * (size_t)NPIX];
            float v1 = base[1 * (size_t)NPIX];
            float v2 = base[2 * (size_t)NPIX];
            float v3 = base[3 * (size_t)NPIX];
            float m = fmaxf(fmaxf(v0, v1), fmaxf(v2, v3));
            float e0 = expf(v0 - m), e1 = expf(v1 - m), e2 = expf(v2 - m), e3 = expf(v3 - m);
            float inv = 1.0f / (e0 + e1 + e2 + e3);
            float p[4] = { e0 * inv, e1 * inv, e2 * inv, e3 * inv };

            int tc = target[((size_t)b * HH + y) * WW + x];

            #pragma unroll
            for (int c = 0; c < 4; ++c) {
                unsigned long long bp = __ballot(p[c] > 0.5f);
                unsigned long long bt = __ballot(tc == c);
                if ((t & 63) == 0) {
                    size_t mi = ((size_t)(b * NC + c)) * 2;
                    masks[((mi + 0) * 4 + w) * HH + y] = bp;
                    masks[((mi + 1) * 4 + w) * HH + y] = bt;
                }
            }
        }
        __threadfence();                    // release: masks visible device-wide
        if (t == 0) atomicAdd(&ready[b], 1);
    }

    // ---------------- consumer ----------------
    int img = bid >> 5;
    int xbase = (bid & 31) << 3;
    int b2 = img >> 2, c2 = img & 3;

    if (t == 0) {
        while (__hip_atomic_load(&ready[b2], __ATOMIC_ACQUIRE, __HIP_MEMORY_SCOPE_AGENT) < 64) {
            __builtin_amdgcn_s_sleep(4);
        }
    }
    __syncthreads();
    __threadfence();                        // acquire side: invalidate stale cache lines

    __shared__ unsigned long long sm[2048];     // [src*4+w][y], 16 KB
    __shared__ int hP[8 * PAD], hT[8 * PAD];    // [cx][y] padded
    __shared__ float pe_s[8 * PAD];
    __shared__ int sF[2][8];
    __shared__ float sred[8];

    const unsigned long long* mb = masks + (size_t)img * 2048;
    #pragma unroll
    for (int j = 0; j < 4; ++j) sm[t + 512 * j] = mb[t + 512 * j];
    __syncthreads();

    // image-wide any(fg) flags from per-row ORs (threads 0..255 hold rows)
    bool anyP = false, anyT = false;
    if (t < 256) {
        unsigned long long rp = sm[0 * HH + t] | sm[1 * HH + t] | sm[2 * HH + t] | sm[3 * HH + t];
        unsigned long long rt = sm[4 * HH + t] | sm[5 * HH + t] | sm[6 * HH + t] | sm[7 * HH + t];
        anyP = (rp != 0ull); anyT = (rt != 0ull);
    }
    unsigned long long bP = __ballot(anyP), bT = __ballot(anyT);
    if (lane == 0) { sF[0][wv] = (bP != 0ull); sF[1][wv] = (bT != 0ull); }

    // Phase A: 4 pixels/thread, lanes row-major within the 8-col strip
    #pragma unroll
    for (int j = 0; j < 4; ++j) {
        int idx = t + 512 * j;          // [0, 2048)
        int cx = idx & 7, y = idx >> 3;
        int x = xbase + cx;

        unsigned long long mp[4], mt[4];
        #pragma unroll
        for (int w = 0; w < 4; ++w) {
            mp[w] = sm[w * HH + y];
            mt[w] = sm[(4 + w) * HH + y];
        }
        int fgP = (int)((mp[x >> 6] >> (x & 63)) & 1);
        int fgT = (int)((mt[x >> 6] >> (x & 63)) & 1);

        unsigned long long sel[4];
        unsigned long long flip = fgP ? ~0ull : 0ull;
        #pragma unroll
        for (int w = 0; w < 4; ++w) sel[w] = mp[w] ^ flip;
        int dP = nearest_dist(sel, x);
        int vP = (dP > 255) ? INF_G : dP * dP;
        hP[cx * PAD + y] = vP | (fgP << 31);

        flip = fgT ? ~0ull : 0ull;
        #pragma unroll
        for (int w = 0; w < 4; ++w) sel[w] = mt[w] ^ flip;
        int dT = nearest_dist(sel, x);
        int vT = (dT > 255) ? INF_G : dT * dT;
        hT[cx * PAD + y] = vT | (fgT << 31);

        // softmax pe (bitwise-identical expression to producer)
        const float* basep = pred + ((size_t)b2 * NC) * NPIX + (size_t)y * WW + x;
        float v0 = basep[0 * (size_t)NPIX];
        float v1 = basep[1 * (size_t)NPIX];
        float v2 = basep[2 * (size_t)NPIX];
        float v3 = basep[3 * (size_t)NPIX];
        float m = fmaxf(fmaxf(v0, v1), fmaxf(v2, v3));
        float e0 = expf(v0 - m), e1 = expf(v1 - m), e2 = expf(v2 - m), e3 = expf(v3 - m);
        float inv = 1.0f / (e0 + e1 + e2 + e3);
        float pc = (c2 == 0) ? e0 * inv : (c2 == 1) ? e1 * inv : (c2 == 2) ? e2 * inv : e3 * inv;
        float d = pc - (float)fgT;
        pe_s[cx * PAD + y] = d * d;
    }
    __syncthreads();

    int hs1 = sF[0][0] | sF[0][1] | sF[0][2] | sF[0][3] | sF[0][4] | sF[0][5] | sF[0][6] | sF[0][7];
    int hs3 = sF[1][0] | sF[1][1] | sF[1][2] | sF[1][3] | sF[1][4] | sF[1][5] | sF[1][6] | sF[1][7];

    // Phase B: lanes vary y; 4 columns/thread
    float acc = 0.0f;
    int y = t & 255, cg2 = t >> 8;      // cg2 in 0..1
    #pragma unroll
    for (int i = 0; i < 4; ++i) {
        int cx = cg2 * 4 + i;
        const int* hp = &hP[cx * PAD];
        const int* ht = &hT[cx * PAD];

        int selfP = hp[y];
        int msP = selfP & 0x80000000;
        int best = selfP & 0x7fffffff;
        for (int s = 1; s < HH; ++s) {
            int ss = s * s;
            if (ss >= best) break;
            int jm = y - s, jp = y + s;
            if (jm >= 0) {
                int hsv = hp[jm];
                int cand = (((hsv ^ msP) & 0x80000000) == 0) ? (hsv & 0x7fffffff) + ss : ss;
                best = min(best, cand);
            }
            if (jp < HH) {
                int hsv = hp[jp];
                int cand = (((hsv ^ msP) & 0x80000000) == 0) ? (hsv & 0x7fffffff) + ss : ss;
                best = min(best, cand);
            }
        }
        float dtP = (best >= INF_G) ? sqrtf(1.0e9f) : sqrtf((float)best);

        int selfT = ht[y];
        int msT = selfT & 0x80000000;
        best = selfT & 0x7fffffff;
        for (int s = 1; s < HH; ++s) {
            int ss = s * s;
            if (ss >= best) break;
            int jm = y - s, jp = y + s;
            if (jm >= 0) {
                int hsv = ht[jm];
                int cand = (((hsv ^ msT) & 0x80000000) == 0) ? (hsv & 0x7fffffff) + ss : ss;
                best = min(best, cand);
            }
            if (jp < HH) {
                int hsv = ht[jp];
                int cand = (((hsv ^ msT) & 0x80000000) == 0) ? (hsv & 0x7fffffff) + ss : ss;
                best = min(best, cand);
            }
        }
        float dtT = (best >= INF_G) ? sqrtf(1.0e9f) : sqrtf((float)best);

        float pd = hs1 ? dtP : 0.0f;    // the pair's other member is exactly 0
        float td = hs3 ? dtT : 0.0f;
        acc += pe_s[cx * PAD + y] * (pd * pd + td * td);
    }

    acc = wave_reduce(acc);
    if (lane == 0) sred[wv] = acc;
    __syncthreads();
    if (t == 0) {
        float bs = sred[0] + sred[1] + sred[2] + sred[3] + sred[4] + sred[5] + sred[6] + sred[7];
        unsafeAtomicAdd(ws_out, bs * (1.0f / (float)TOTAL));
        __threadfence();
        int d = atomicAdd(done, 1);
        if (d == 511) {
            float tot = unsafeAtomicAdd(ws_out, 0.0f);   // returns old = final sum
            out[0] = tot;
        }
    }
}

extern "C" void kernel_launch(void* const* d_in, const int* in_sizes, int n_in,
                              void* d_out, int out_size, void* d_ws, size_t ws_size,
                              hipStream_t stream) {
    const float* pred  = (const float*)d_in[0];
    const int* target  = (const int*)d_in[1];
    float* out = (float*)d_out;

    unsigned long long* masks = (unsigned long long*)d_ws;   // 16*2048 u64 = 256 KB
    char* ctrl = (char*)d_ws + 262144;
    int*   ready  = (int*)ctrl;                              // 4 ints
    int*   done   = (int*)(ctrl + 16);                       // 1 int
    float* ws_out = (float*)(ctrl + 20);                     // 1 float

    hipMemsetAsync(ctrl, 0, 32, stream);
    fused_all<<<512, 512, 0, stream>>>(pred, target, masks, ready, done, ws_out, out);
}

// Round 17
// 28.256 us; speedup vs baseline: 5.2206x; 5.2206x over previous
//
#include <hip/hip_runtime.h>

#define HH 256
#define WW 256
#define NB 4
#define NC 4
#define NPIX (HH*WW)            // 65536
#define NIMG (NB*NC)            // 16
#define TOTAL (NB*NC*HH*WW)     // 1048576
#define INF_G (1<<30)
#define PAD 257

__device__ __forceinline__ float wave_reduce(float v) {
    #pragma unroll
    for (int off = 32; off > 0; off >>= 1) v += __shfl_down(v, off);
    return v;
}

// distance from x to nearest set bit in a 256-bit mask (4 u64 words); INT_MAX if none
__device__ __forceinline__ int nearest_dist(const unsigned long long* m, int x) {
    int best = 0x7fffffff;
    #pragma unroll
    for (int w = 0; w < 4; ++w) {
        unsigned long long mm = m[w];
        if (!mm) continue;
        int rel = x - (w << 6);
        unsigned long long lmask = (rel >= 63) ? ~0ull
                                 : ((rel < 0) ? 0ull : ((2ull << (rel & 63)) - 1ull));
        unsigned long long lm = mm & lmask;
        if (lm) best = min(best, rel - (63 - __clzll(lm)));
        unsigned long long rmask = (rel <= 0) ? ~0ull
                                 : ((rel > 63) ? 0ull : (~0ull << (rel & 63)));
        unsigned long long rm = mm & rmask;
        if (rm) best = min(best, (__ffsll((long long)rm) - 1) - rel);
    }
    return best;
}

// K1: softmax + row ballot masks. 256 blocks x 1024 threads; block = (b, 4-row group).
// Wave layout: y constant per wave, x spans one aligned 64-px word -> the wave
// ballot IS the mask word; lane 0 stores it directly. No LDS, no barrier.
// masks layout: [img][src][w][y] -> masks[(((img*2)+src)*4+w)*HH + y]  (y fastest)
// Also zeroes out[0] (timed replays don't re-poison; kernel boundary publishes it).
__global__ __launch_bounds__(1024) void build_masks(
        const float* __restrict__ pred, const int* __restrict__ target,
        unsigned long long* __restrict__ masks, float* __restrict__ out) {
    int bid = blockIdx.x;           // b*64 + rowgroup
    int t = threadIdx.x;
    int b = bid >> 6, rg = bid & 63;
    int x = t & 255;
    int y = (rg << 2) + (t >> 8);
    int w = x >> 6;                 // word index within the row

    if (bid == 0 && t == 0) out[0] = 0.0f;

    const float* base = pred + (((size_t)b * NC) * HH + y) * WW + x;
    float v0 = base[0 * (size_t)NPIX];
    float v1 = base[1 * (size_t)NPIX];
    float v2 = base[2 * (size_t)NPIX];
    float v3 = base[3 * (size_t)NPIX];
    float m = fmaxf(fmaxf(v0, v1), fmaxf(v2, v3));
    float e0 = expf(v0 - m), e1 = expf(v1 - m), e2 = expf(v2 - m), e3 = expf(v3 - m);
    float inv = 1.0f / (e0 + e1 + e2 + e3);
    float p[4] = { e0 * inv, e1 * inv, e2 * inv, e3 * inv };

    int tc = target[((size_t)b * HH + y) * WW + x];

    #pragma unroll
    for (int c = 0; c < 4; ++c) {
        unsigned long long bp = __ballot(p[c] > 0.5f);
        unsigned long long bt = __ballot(tc == c);
        if ((t & 63) == 0) {
            size_t mi = ((size_t)(b * NC + c)) * 2;
            masks[((mi + 0) * 4 + w) * HH + y] = bp;
            masks[((mi + 1) * 4 + w) * HH + y] = bt;
        }
    }
}

// K2: block = (img, 8-col strip), 1024 threads, 512 blocks (2 blocks/CU, 32 waves/CU).
// Phase A (row-major lanes, 2 px/thread): nearest-opposite-set row distance
//   (fg in sign bit) + softmax pe -> padded LDS.
// Phase B (column lanes, 2 cols/thread): outward column search with early exit;
//   loss; one fp32 atomic per block.
__global__ __launch_bounds__(1024) void cols_loss(const unsigned long long* __restrict__ masks,
                                                  const float* __restrict__ pred,
                                                  float* __restrict__ out) {
    int bid = blockIdx.x;
    int img = bid >> 5;
    int xbase = (bid & 31) << 3;
    int b = img >> 2, c = img & 3;
    int t = threadIdx.x;
    int lane = t & 63, wv = t >> 6;

    __shared__ unsigned long long sm[2048];     // [src*4+w][y], 16 KB
    __shared__ int hP[8 * PAD], hT[8 * PAD];    // [cx][y] padded
    __shared__ float pe_s[8 * PAD];
    __shared__ int sF[2][16];
    __shared__ float sred[16];

    const unsigned long long* mb = masks + (size_t)img * 2048;
    #pragma unroll
    for (int j = 0; j < 2; ++j) sm[t + 1024 * j] = mb[t + 1024 * j];
    __syncthreads();

    // image-wide any(fg) flags from per-row ORs (threads 0..255 hold rows)
    bool anyP = false, anyT = false;
    if (t < 256) {
        unsigned long long rp = sm[0 * HH + t] | sm[1 * HH + t] | sm[2 * HH + t] | sm[3 * HH + t];
        unsigned long long rt = sm[4 * HH + t] | sm[5 * HH + t] | sm[6 * HH + t] | sm[7 * HH + t];
        anyP = (rp != 0ull); anyT = (rt != 0ull);
    }
    unsigned long long bP = __ballot(anyP), bT = __ballot(anyT);
    if (lane == 0) { sF[0][wv] = (bP != 0ull); sF[1][wv] = (bT != 0ull); }

    // Phase A: 2 pixels/thread, lanes row-major within the 8-col strip
    #pragma unroll
    for (int j = 0; j < 2; ++j) {
        int idx = t + 1024 * j;         // [0, 2048)
        int cx = idx & 7, y = idx >> 3;
        int x = xbase + cx;

        unsigned long long mp[4], mt[4];
        #pragma unroll
        for (int w = 0; w < 4; ++w) {
            mp[w] = sm[w * HH + y];
            mt[w] = sm[(4 + w) * HH + y];
        }
        int fgP = (int)((mp[x >> 6] >> (x & 63)) & 1);
        int fgT = (int)((mt[x >> 6] >> (x & 63)) & 1);

        unsigned long long sel[4];
        unsigned long long flip = fgP ? ~0ull : 0ull;
        #pragma unroll
        for (int w = 0; w < 4; ++w) sel[w] = mp[w] ^ flip;
        int dP = nearest_dist(sel, x);
        int vP = (dP > 255) ? INF_G : dP * dP;
        hP[cx * PAD + y] = vP | (fgP << 31);

        flip = fgT ? ~0ull : 0ull;
        #pragma unroll
        for (int w = 0; w < 4; ++w) sel[w] = mt[w] ^ flip;
        int dT = nearest_dist(sel, x);
        int vT = (dT > 255) ? INF_G : dT * dT;
        hT[cx * PAD + y] = vT | (fgT << 31);

        // softmax pe (bitwise-identical expression to k1)
        const float* basep = pred + ((size_t)b * NC) * NPIX + (size_t)y * WW + x;
        float v0 = basep[0 * (size_t)NPIX];
        float v1 = basep[1 * (size_t)NPIX];
        float v2 = basep[2 * (size_t)NPIX];
        float v3 = basep[3 * (size_t)NPIX];
        float m = fmaxf(fmaxf(v0, v1), fmaxf(v2, v3));
        float e0 = expf(v0 - m), e1 = expf(v1 - m), e2 = expf(v2 - m), e3 = expf(v3 - m);
        float inv = 1.0f / (e0 + e1 + e2 + e3);
        float pc = (c == 0) ? e0 * inv : (c == 1) ? e1 * inv : (c == 2) ? e2 * inv : e3 * inv;
        float d = pc - (float)fgT;
        pe_s[cx * PAD + y] = d * d;
    }
    __syncthreads();

    int hs1 = 0, hs3 = 0;
    #pragma unroll
    for (int i = 0; i < 16; ++i) { hs1 |= sF[0][i]; hs3 |= sF[1][i]; }

    // Phase B: lanes vary y; 2 columns/thread
    float acc = 0.0f;
    int y = t & 255, cg2 = t >> 8;      // cg2 in 0..3
    #pragma unroll
    for (int i = 0; i < 2; ++i) {
        int cx = cg2 * 2 + i;
        const int* hp = &hP[cx * PAD];
        const int* ht = &hT[cx * PAD];

        int selfP = hp[y];
        int msP = selfP & 0x80000000;
        int best = selfP & 0x7fffffff;
        for (int s = 1; s < HH; ++s) {
            int ss = s * s;
            if (ss >= best) break;
            int jm = y - s, jp = y + s;
            if (jm >= 0) {
                int hsv = hp[jm];
                int cand = (((hsv ^ msP) & 0x80000000) == 0) ? (hsv & 0x7fffffff) + ss : ss;
                best = min(best, cand);
            }
            if (jp < HH) {
                int hsv = hp[jp];
                int cand = (((hsv ^ msP) & 0x80000000) == 0) ? (hsv & 0x7fffffff) + ss : ss;
                best = min(best, cand);
            }
        }
        float dtP = (best >= INF_G) ? sqrtf(1.0e9f) : sqrtf((float)best);

        int selfT = ht[y];
        int msT = selfT & 0x80000000;
        best = selfT & 0x7fffffff;
        for (int s = 1; s < HH; ++s) {
            int ss = s * s;
            if (ss >= best) break;
            int jm = y - s, jp = y + s;
            if (jm >= 0) {
                int hsv = ht[jm];
                int cand = (((hsv ^ msT) & 0x80000000) == 0) ? (hsv & 0x7fffffff) + ss : ss;
                best = min(best, cand);
            }
            if (jp < HH) {
                int hsv = ht[jp];
                int cand = (((hsv ^ msT) & 0x80000000) == 0) ? (hsv & 0x7fffffff) + ss : ss;
                best = min(best, cand);
            }
        }
        float dtT = (best >= INF_G) ? sqrtf(1.0e9f) : sqrtf((float)best);

        float pd = hs1 ? dtP : 0.0f;    // the pair's other member is exactly 0
        float td = hs3 ? dtT : 0.0f;
        acc += pe_s[cx * PAD + y] * (pd * pd + td * td);
    }

    acc = wave_reduce(acc);
    if (lane == 0) sred[wv] = acc;
    __syncthreads();
    if (t == 0) {
        float bs = 0.0f;
        #pragma unroll
        for (int i = 0; i < 16; ++i) bs += sred[i];
        unsafeAtomicAdd(out, bs * (1.0f / (float)TOTAL));
    }
}

extern "C" void kernel_launch(void* const* d_in, const int* in_sizes, int n_in,
                              void* d_out, int out_size, void* d_ws, size_t ws_size,
                              hipStream_t stream) {
    const float* pred  = (const float*)d_in[0];
    const int* target  = (const int*)d_in[1];
    float* out = (float*)d_out;

    unsigned long long* masks = (unsigned long long*)d_ws;   // 16*2048 u64 = 256 KB

    build_masks<<<NB * 64, 1024, 0, stream>>>(pred, target, masks, out);
    cols_loss<<<NIMG * 32, 1024, 0, stream>>>(masks, pred, out);
}